// Round 6
// baseline (843.973 us; speedup 1.0000x reference)
//
#include <hip/hip_runtime.h>

#define N_MET 250000
#define N_RXN 500000
#define N_RXN_PAD 500032   // padded rows for T so MFMA tail tiles stay in-bounds
#define E_SUB 2000000
#define E_ALL 4000000
#define DT 0.01f

#define RXN_PER_BLK 256
#define THREADS 256
#define EDGE_CAP 1536   // Poisson(1024) +16 sigma; global fallback below

#define MV_RPB 64       // k_mv reactions per block (4 waves x 16)

#define SCAN_T 256
#define SCAN_V 8
#define SCAN_CHUNK (SCAN_T * SCAN_V)
#define SCAN_NB ((N_RXN + SCAN_CHUNK - 1) / SCAN_CHUNK)
static_assert(SCAN_NB <= SCAN_T, "scan2 single block must cover all block sums");

typedef int v4i __attribute__((ext_vector_type(4)));
typedef float v4f __attribute__((ext_vector_type(4)));
typedef short bf16x8 __attribute__((ext_vector_type(8)));
typedef float f32x4 __attribute__((ext_vector_type(4)));

static __device__ __forceinline__ float fast_tanh(float x) {
  float e = __expf(x + x);
  return 1.0f - __fdividef(2.0f, e + 1.0f);
}

static __device__ __forceinline__ void atomic_add_f32(float* p, float v) {
  __hip_atomic_fetch_add(p, v, __ATOMIC_RELAXED, __HIP_MEMORY_SCOPE_AGENT);
}

static __device__ __forceinline__ int bcast_i(int v, int lane) {
  return __builtin_amdgcn_readlane(v, lane);
}

static __device__ __forceinline__ unsigned short bf16_rn(float f) {
  unsigned u = __float_as_uint(f);
  unsigned r = u + 0x7FFFu + ((u >> 16) & 1u);
  return (unsigned short)(r >> 16);
}

// ---- precompute MFMA B-fragments of W23 = W2@W3 (bf16 hi/lo) and b2@W3 ----
// B-frag layout (16x16x32 bf16): lane l holds B[k=(l>>4)*8+t][n=l&15], t=0..7.
// Frag index: (ks*4 + jt)*64 + lane, covering k = ks*32+..., n = jt*16+...
__global__ void k_pre(const float* __restrict__ W2, const float* __restrict__ W3,
                      const float* __restrict__ b2,
                      uint4* __restrict__ wfh, uint4* __restrict__ wfl,
                      float* __restrict__ b2w3) {
  int tid = blockIdx.x * blockDim.x + threadIdx.x;
  if (tid < 512) {
    int lane = tid & 63, jt = (tid >> 6) & 3, ks = tid >> 8;
    int jj = jt * 16 + (lane & 15);
    unsigned short h[8], l[8];
    #pragma unroll
    for (int t = 0; t < 8; ++t) {
      int kk = ks * 32 + (lane >> 4) * 8 + t;
      float w = 0.f;
      #pragma unroll
      for (int m = 0; m < 32; ++m) w = fmaf(W2[kk * 32 + m], W3[m * 64 + jj], w);
      h[t] = bf16_rn(w);
      float hf = __uint_as_float(((unsigned)h[t]) << 16);
      l[t] = bf16_rn(w - hf);
    }
    uint4 H, L;
    H.x = (unsigned)h[0] | ((unsigned)h[1] << 16);
    H.y = (unsigned)h[2] | ((unsigned)h[3] << 16);
    H.z = (unsigned)h[4] | ((unsigned)h[5] << 16);
    H.w = (unsigned)h[6] | ((unsigned)h[7] << 16);
    L.x = (unsigned)l[0] | ((unsigned)l[1] << 16);
    L.y = (unsigned)l[2] | ((unsigned)l[3] << 16);
    L.z = (unsigned)l[4] | ((unsigned)l[5] << 16);
    L.w = (unsigned)l[6] | ((unsigned)l[7] << 16);
    int idx = (ks * 4 + jt) * 64 + lane;
    wfh[idx] = H; wfl[idx] = L;
  }
  if (tid < 64) {
    float t = 0.f;
    #pragma unroll
    for (int m = 0; m < 32; ++m) t = fmaf(b2[m], W3[m * 64 + tid], t);
    b2w3[tid] = t;
  }
}

// ---- histogram + dense conc extraction ----
__global__ void k_hist(const int* __restrict__ rxn_sub, const float* __restrict__ x,
                       int* __restrict__ counts, float* __restrict__ conc) {
  int t = blockIdx.x * blockDim.x + threadIdx.x;
  if (t < E_SUB / 4) {
    v4i r = __builtin_nontemporal_load((const v4i*)rxn_sub + t);
    atomicAdd(&counts[r.x], 1);
    atomicAdd(&counts[r.y], 1);
    atomicAdd(&counts[r.z], 1);
    atomicAdd(&counts[r.w], 1);
  }
  if (t < N_MET) conc[t] = __builtin_nontemporal_load(x + t * 8 + 3);
}

__global__ void k_scan1(const int* __restrict__ counts, int* __restrict__ bsums) {
  __shared__ int ss[SCAN_T];
  int b = blockIdx.x, t = threadIdx.x;
  int base = b * SCAN_CHUNK + t * SCAN_V;
  int s = 0;
  #pragma unroll
  for (int k = 0; k < SCAN_V; ++k) { int i = base + k; if (i < N_RXN) s += counts[i]; }
  ss[t] = s; __syncthreads();
  for (int d = SCAN_T / 2; d > 0; d >>= 1) {
    if (t < d) ss[t] += ss[t + d];
    __syncthreads();
  }
  if (t == 0) bsums[b] = ss[0];
}

__global__ void k_scan2(int* __restrict__ bsums) {
  __shared__ int ss[SCAN_T];
  int t = threadIdx.x;
  int v = (t < SCAN_NB) ? bsums[t] : 0;
  ss[t] = v; __syncthreads();
  for (int d = 1; d < SCAN_T; d <<= 1) {
    int a = (t >= d) ? ss[t - d] : 0;
    __syncthreads();
    ss[t] += a;
    __syncthreads();
  }
  if (t < SCAN_NB) bsums[t] = ss[t] - v;  // exclusive
}

__global__ void k_scan3(const int* __restrict__ counts, const int* __restrict__ bsums,
                        int* __restrict__ off, int* __restrict__ cursor,
                        float2* __restrict__ vr) {
  __shared__ int ss[SCAN_T];
  int b = blockIdx.x, t = threadIdx.x;
  int base = b * SCAN_CHUNK + t * SCAN_V;
  int v[SCAN_V];
  int s = 0;
  #pragma unroll
  for (int k = 0; k < SCAN_V; ++k) { int i = base + k; v[k] = (i < N_RXN) ? counts[i] : 0; s += v[k]; }
  ss[t] = s; __syncthreads();
  for (int d = 1; d < SCAN_T; d <<= 1) {
    int a = (t >= d) ? ss[t - d] : 0;
    __syncthreads();
    ss[t] += a;
    __syncthreads();
  }
  int run = bsums[b] + ss[t] - s;
  #pragma unroll
  for (int k = 0; k < SCAN_V; ++k) {
    int i = base + k;
    if (i < N_RXN) {
      off[i] = run; cursor[i] = run;
      vr[i] = make_float2(0.f, 1.0f);
    }
    run += v[k];
  }
  if (b == 0 && t == 0) off[N_RXN] = E_SUB;
}

// ---- scatter into CSR order: ONE 16B record per edge {conc, sto, bitcast(m), 0} ----
__global__ void k_scatter(const int* __restrict__ rxn_sub, const int* __restrict__ met_sub,
                          const float* __restrict__ sto_sub, const float* __restrict__ conc,
                          int* __restrict__ cursor, float4* __restrict__ edges) {
  int e = blockIdx.x * blockDim.x + threadIdx.x;
  if (e < E_SUB) {
    int r = __builtin_nontemporal_load(rxn_sub + e);
    int m = __builtin_nontemporal_load(met_sub + e);
    float st = __builtin_nontemporal_load(sto_sub + e);
    int pos = atomicAdd(&cursor[r], 1);
    edges[pos] = make_float4(conc[m], st, __int_as_float(m), 0.f);
  }
}

// ---- k_edge: wave-per-reaction edge tanh-sum; T -> bf16 hi/lo, row-major [r][64] ----
template <typename EP>
static __device__ __forceinline__ float edge_sum(int o0, int o1, int estart, EP ep,
                                                 float w1x, float w1y, float b1j) {
  float T0 = 0.f, T1 = 0.f;
  int c = o0;
  for (; c + 1 < o1; c += 2) {
    float4 e0 = ep[c - estart];
    float4 e1 = ep[c + 1 - estart];
    T0 += fast_tanh(fmaf(e0.x, w1x, fmaf(e0.y, w1y, b1j)));
    T1 += fast_tanh(fmaf(e1.x, w1x, fmaf(e1.y, w1y, b1j)));
  }
  if (c < o1) {
    float4 e0 = ep[c - estart];
    T0 += fast_tanh(fmaf(e0.x, w1x, fmaf(e0.y, w1y, b1j)));
  }
  return T0 + T1;
}

__global__ __launch_bounds__(THREADS) void k_edge(
    const int* __restrict__ off, const float4* __restrict__ edges,
    const float* __restrict__ W1, const float* __restrict__ b1,
    unsigned short* __restrict__ Thi, unsigned short* __restrict__ Tlo, int use_lo) {
  __shared__ int off_s[RXN_PER_BLK + 1];
  __shared__ float4 se[EDGE_CAP];

  int tid = threadIdx.x;
  int lane = tid & 63;
  int wv = tid >> 6;
  int R0 = blockIdx.x * RXN_PER_BLK;

  for (int i = tid; i <= RXN_PER_BLK; i += THREADS) {
    int r = R0 + i;
    off_s[i] = off[r > N_RXN ? N_RXN : r];
  }
  __syncthreads();
  int estart = off_s[0];
  int nE = off_s[RXN_PER_BLK] - estart;
  bool fits = (nE <= EDGE_CAP);
  if (fits) {
    for (int i = tid; i < nE; i += THREADS) se[i] = edges[estart + i];
  }

  float w1x = W1[lane], w1y = W1[64 + lane], b1j = b1[lane];

  int rbase = R0 + wv * 64;
  int o0l = off_s[wv * 64 + lane];
  int o1l = off_s[wv * 64 + lane + 1];

  __syncthreads();

  #pragma clang loop unroll(disable)
  for (int i = 0; i < 64; ++i) {
    int r = rbase + i;
    if (r >= N_RXN) break;  // uniform
    int o0 = bcast_i(o0l, i), o1 = bcast_i(o1l, i);
    float T = fits ? edge_sum(o0, o1, estart, (const float4*)se, w1x, w1y, b1j)
                   : edge_sum(o0, o1, estart, edges + estart, w1x, w1y, b1j);
    unsigned short hi = bf16_rn(T);
    Thi[r * 64 + lane] = hi;
    if (use_lo) {
      float hf = __uint_as_float(((unsigned)hi) << 16);
      Tlo[r * 64 + lane] = bf16_rn(T - hf);
    }
  }
}

// ---- k_mv: U = T @ W23 via MFMA (bf16 hi/lo), fused epilogue + consumption ----
__global__ __launch_bounds__(256) void k_mv(
    const int* __restrict__ off, const float4* __restrict__ edges,
    const unsigned short* __restrict__ Thi, const unsigned short* __restrict__ Tlo,
    const uint4* __restrict__ wfh, const uint4* __restrict__ wfl,
    const float* __restrict__ b2w3, const float* __restrict__ b3,
    const float* __restrict__ W4, const float* __restrict__ b4,
    const float* __restrict__ log_k, int use_lo,
    float2* __restrict__ vr, float* __restrict__ total) {
  __shared__ int soff[MV_RPB + 1];
  int tid = threadIdx.x, lane = tid & 63, w = tid >> 6;
  int B0 = blockIdx.x * MV_RPB;
  for (int i = tid; i <= MV_RPB; i += 256) {
    int r = B0 + i;
    soff[i] = off[r > N_RXN ? N_RXN : r];
  }
  __syncthreads();

  int R0 = B0 + w * 16;
  int col = lane & 15, rowg = lane >> 4;

  // A-frags: lane l holds T[R0 + (l&15)][ks*32 + (l>>4)*8 + 0..7]
  bf16x8 ah[2], al[2];
  {
    int rowelem = (R0 + col) * 64 + rowg * 8;
    const uint4* ph = (const uint4*)Thi;
    ah[0] = __builtin_bit_cast(bf16x8, ph[rowelem >> 3]);
    ah[1] = __builtin_bit_cast(bf16x8, ph[(rowelem + 32) >> 3]);
    if (use_lo) {
      const uint4* pl = (const uint4*)Tlo;
      al[0] = __builtin_bit_cast(bf16x8, pl[rowelem >> 3]);
      al[1] = __builtin_bit_cast(bf16x8, pl[(rowelem + 32) >> 3]);
    }
  }

  f32x4 acc[4];
  #pragma unroll
  for (int jt = 0; jt < 4; ++jt) acc[jt] = (f32x4){0.f, 0.f, 0.f, 0.f};

  #pragma unroll
  for (int jt = 0; jt < 4; ++jt) {
    #pragma unroll
    for (int ks = 0; ks < 2; ++ks) {
      int bidx = (ks * 4 + jt) * 64 + lane;
      bf16x8 bh = __builtin_bit_cast(bf16x8, wfh[bidx]);
      acc[jt] = __builtin_amdgcn_mfma_f32_16x16x32_bf16(ah[ks], bh, acc[jt], 0, 0, 0);
      if (use_lo) {
        bf16x8 bl = __builtin_bit_cast(bf16x8, wfl[bidx]);
        acc[jt] = __builtin_amdgcn_mfma_f32_16x16x32_bf16(ah[ks], bl, acc[jt], 0, 0, 0);
        acc[jt] = __builtin_amdgcn_mfma_f32_16x16x32_bf16(al[ks], bh, acc[jt], 0, 0, 0);
      }
    }
  }

  // per-lane params for its column j = jt*16 + col
  float w4c[4], bwc[4], b3c[4];
  #pragma unroll
  for (int jt = 0; jt < 4; ++jt) {
    int jj = jt * 16 + col;
    w4c[jt] = W4[jj]; bwc[jt] = b2w3[jj]; b3c[jt] = b3[jj];
  }
  float b40 = b4[0];

  // edge counts for this lane's 4 reactions (rows rowg*4+q)
  float nq[4];
  #pragma unroll
  for (int q = 0; q < 4; ++q) {
    int idx = w * 16 + rowg * 4 + q;
    nq[q] = (float)(soff[idx + 1] - soff[idx]);
  }

  // z[q] = sum_j tanh(u_j) * W4_j  (reduce over the 16 col-lanes)
  float vq[4];
  #pragma unroll
  for (int q = 0; q < 4; ++q) {
    float s = 0.f;
    #pragma unroll
    for (int jt = 0; jt < 4; ++jt) {
      float u = acc[jt][q] + nq[q] * bwc[jt] + b3c[jt];
      s += fast_tanh(u) * w4c[jt];
    }
    s += __shfl_xor(s, 1, 64);
    s += __shfl_xor(s, 2, 64);
    s += __shfl_xor(s, 4, 64);
    s += __shfl_xor(s, 8, 64);
    int r = R0 + rowg * 4 + q;
    float lk = (r < N_RXN) ? log_k[r] : 0.f;
    float racc = s + b40;
    float k10 = __expf(lk * 2.3025850929940457f);
    float sp = (racc > 15.f) ? racc : __logf(1.f + __expf(racc));
    vq[q] = k10 * sp;
  }

  if (col == 0) {
    #pragma unroll
    for (int q = 0; q < 4; ++q) {
      int r = R0 + rowg * 4 + q;
      if (r < N_RXN) vr[r].x = vq[q];
    }
  }

  // consumption: 4 lanes per reaction walk its CSR slice
  int rloc = lane >> 2;                    // wave-local rxn 0..15; rowg(rloc)==lane>>4
  float vmine = vq[(lane >> 2) & 3];
  float vdt = vmine * DT;
  int o0 = soff[w * 16 + rloc], o1 = soff[w * 16 + rloc + 1];
  for (int c = o0 + (lane & 3); c < o1; c += 4) {
    float4 e = edges[c];
    atomic_add_f32(&total[__float_as_int(e.z)], e.y * vdt);
  }
}

__global__ void k_scale(const float* __restrict__ total, const float* __restrict__ conc,
                        float* __restrict__ met_scale) {
  int m = blockIdx.x * blockDim.x + threadIdx.x;
  if (m < N_MET) {
    float tot = total[m];
    float cc = conc[m];
    met_scale[m] = (tot > 1e-12f) ? fminf(cc / tot, 1.0f) : 1.0f;
  }
}

__global__ void k_minscale(const int* __restrict__ met_sub, const int* __restrict__ rxn_sub,
                           const float* __restrict__ met_scale, float2* __restrict__ vr) {
  int e = blockIdx.x * blockDim.x + threadIdx.x;
  if (e < E_SUB) {
    int m = __builtin_nontemporal_load(met_sub + e);
    int r = __builtin_nontemporal_load(rxn_sub + e);
    unsigned s = __float_as_uint(met_scale[m]);
    atomicMin((unsigned*)&vr[r].y, s);
  }
}

__global__ void k_contrib(const int* __restrict__ met_all, const int* __restrict__ rxn_all,
                          const float* __restrict__ sto_all, const float2* __restrict__ vr,
                          float* __restrict__ dxdt) {
  int t = blockIdx.x * blockDim.x + threadIdx.x;
  if (t < E_ALL / 4) {
    v4i me = __builtin_nontemporal_load((const v4i*)met_all + t);
    v4i re = __builtin_nontemporal_load((const v4i*)rxn_all + t);
    v4f se = __builtin_nontemporal_load((const v4f*)sto_all + t);
    float2 g0 = vr[re.x], g1 = vr[re.y], g2 = vr[re.z], g3 = vr[re.w];
    atomic_add_f32(&dxdt[me.x], se.x * g0.x * g0.y);
    atomic_add_f32(&dxdt[me.y], se.y * g1.x * g1.y);
    atomic_add_f32(&dxdt[me.z], se.z * g2.x * g2.y);
    atomic_add_f32(&dxdt[me.w], se.w * g3.x * g3.y);
  }
}

extern "C" void kernel_launch(void* const* d_in, const int* in_sizes, int n_in,
                              void* d_out, int out_size, void* d_ws, size_t ws_size,
                              hipStream_t stream) {
  const float* x       = (const float*)d_in[0];
  const int*   met_sub = (const int*)d_in[1];
  const int*   rxn_sub = (const int*)d_in[2];
  const float* sto_sub = (const float*)d_in[3];
  const int*   met_all = (const int*)d_in[4];
  const int*   rxn_all = (const int*)d_in[5];
  const float* sto_all = (const float*)d_in[6];
  const float* W1    = (const float*)d_in[7];
  const float* b1    = (const float*)d_in[8];
  const float* W2    = (const float*)d_in[9];
  const float* b2    = (const float*)d_in[10];
  const float* W3    = (const float*)d_in[11];
  const float* b3    = (const float*)d_in[12];
  const float* W4    = (const float*)d_in[13];
  const float* b4    = (const float*)d_in[14];
  const float* log_k = (const float*)d_in[15];
  float* dxdt = (float*)d_out;

  char* ws = (char*)d_ws;
  size_t p = 0;
  auto alloc = [&](size_t bytes) -> void* {
    void* r = (void*)(ws + p);
    p += (bytes + 255) & ~(size_t)255;
    return r;
  };
  int*    counts    = (int*)alloc(sizeof(int) * N_RXN);
  int*    off       = (int*)alloc(sizeof(int) * (N_RXN + 1));
  int*    cursor    = (int*)alloc(sizeof(int) * N_RXN);
  int*    bsums     = (int*)alloc(sizeof(int) * 1024);
  uint4*  wfh       = (uint4*)alloc(sizeof(uint4) * 512);
  uint4*  wfl       = (uint4*)alloc(sizeof(uint4) * 512);
  float*  b2w3      = (float*)alloc(sizeof(float) * 64);
  float2* vr        = (float2*)alloc(sizeof(float2) * N_RXN);   // .x = v_pre, .y = scale
  float*  conc      = (float*)alloc(sizeof(float) * N_MET);
  float*  total     = (float*)alloc(sizeof(float) * N_MET);
  float*  met_scale = (float*)alloc(sizeof(float) * N_MET);
  float4* edges     = (float4*)alloc(sizeof(float4) * E_SUB);   // {conc, sto, m, -}
  unsigned short* Thi = (unsigned short*)alloc(sizeof(unsigned short) * (size_t)N_RXN_PAD * 64);
  size_t tlo_bytes = sizeof(unsigned short) * (size_t)N_RXN_PAD * 64;
  int use_lo = (p + tlo_bytes <= ws_size) ? 1 : 0;
  unsigned short* Tlo = use_lo ? (unsigned short*)alloc(tlo_bytes) : Thi;
  (void)in_sizes; (void)n_in; (void)out_size;

  hipMemsetAsync(counts, 0, sizeof(int) * N_RXN, stream);
  hipMemsetAsync(total, 0, sizeof(float) * N_MET, stream);
  hipMemsetAsync(dxdt, 0, sizeof(float) * N_MET, stream);

  k_pre<<<2, 256, 0, stream>>>(W2, W3, b2, wfh, wfl, b2w3);
  k_hist<<<(E_SUB / 4 + 255) / 256, 256, 0, stream>>>(rxn_sub, x, counts, conc);
  k_scan1<<<SCAN_NB, SCAN_T, 0, stream>>>(counts, bsums);
  k_scan2<<<1, SCAN_T, 0, stream>>>(bsums);
  k_scan3<<<SCAN_NB, SCAN_T, 0, stream>>>(counts, bsums, off, cursor, vr);
  k_scatter<<<(E_SUB + 255) / 256, 256, 0, stream>>>(rxn_sub, met_sub, sto_sub, conc,
                                                     cursor, edges);
  k_edge<<<(N_RXN + RXN_PER_BLK - 1) / RXN_PER_BLK, THREADS, 0, stream>>>(
      off, edges, W1, b1, Thi, Tlo, use_lo);
  k_mv<<<(N_RXN + MV_RPB - 1) / MV_RPB, 256, 0, stream>>>(
      off, edges, Thi, Tlo, wfh, wfl, b2w3, b3, W4, b4, log_k, use_lo, vr, total);
  k_scale<<<(N_MET + 255) / 256, 256, 0, stream>>>(total, conc, met_scale);
  k_minscale<<<(E_SUB + 255) / 256, 256, 0, stream>>>(met_sub, rxn_sub, met_scale, vr);
  k_contrib<<<(E_ALL / 4 + 255) / 256, 256, 0, stream>>>(met_all, rxn_all, sto_all, vr, dxdt);
}

// Round 7
// 761.756 us; speedup vs baseline: 1.1079x; 1.1079x over previous
//
#include <hip/hip_runtime.h>

#define N_MET 250000
#define N_RXN 500000
#define N_RXN_PAD 500032   // padded rows for T so MFMA tail tiles stay in-bounds
#define E_SUB 2000000
#define E_ALL 4000000
#define DT 0.01f

#define RXN_PER_BLK 256
#define THREADS 256
#define EDGE_CAP 1536   // Poisson(1024) +16 sigma; global fallback below

#define MV_RPB 64       // k_mv reactions per block (4 waves x 16)

#define SCAN_T 256
#define SCAN_V 8
#define SCAN_CHUNK (SCAN_T * SCAN_V)
#define SCAN_NB ((N_RXN + SCAN_CHUNK - 1) / SCAN_CHUNK)
static_assert(SCAN_NB <= SCAN_T, "scan2 single block must cover all block sums");

typedef int v4i __attribute__((ext_vector_type(4)));
typedef float v4f __attribute__((ext_vector_type(4)));
typedef short bf16x8 __attribute__((ext_vector_type(8)));
typedef float f32x4 __attribute__((ext_vector_type(4)));

static __device__ __forceinline__ float fast_tanh(float x) {
  float e = __expf(x + x);
  return 1.0f - __fdividef(2.0f, e + 1.0f);
}

static __device__ __forceinline__ void atomic_add_f32(float* p, float v) {
  __hip_atomic_fetch_add(p, v, __ATOMIC_RELAXED, __HIP_MEMORY_SCOPE_AGENT);
}

static __device__ __forceinline__ int bcast_i(int v, int lane) {
  return __builtin_amdgcn_readlane(v, lane);
}

static __device__ __forceinline__ unsigned short bf16_rn(float f) {
  unsigned u = __float_as_uint(f);
  unsigned r = u + 0x7FFFu + ((u >> 16) & 1u);
  return (unsigned short)(r >> 16);
}

// ---- precompute MFMA B-fragments of W23 = W2@W3 (bf16 hi/lo) and b2@W3 ----
// B-frag layout (16x16x32 bf16): lane l holds B[k=(l>>4)*8+t][n=l&15], t=0..7.
__global__ void k_pre(const float* __restrict__ W2, const float* __restrict__ W3,
                      const float* __restrict__ b2,
                      uint4* __restrict__ wfh, uint4* __restrict__ wfl,
                      float* __restrict__ b2w3) {
  int tid = blockIdx.x * blockDim.x + threadIdx.x;
  if (tid < 512) {
    int lane = tid & 63, jt = (tid >> 6) & 3, ks = tid >> 8;
    int jj = jt * 16 + (lane & 15);
    unsigned short h[8], l[8];
    #pragma unroll
    for (int t = 0; t < 8; ++t) {
      int kk = ks * 32 + (lane >> 4) * 8 + t;
      float w = 0.f;
      #pragma unroll
      for (int m = 0; m < 32; ++m) w = fmaf(W2[kk * 32 + m], W3[m * 64 + jj], w);
      h[t] = bf16_rn(w);
      float hf = __uint_as_float(((unsigned)h[t]) << 16);
      l[t] = bf16_rn(w - hf);
    }
    uint4 H, L;
    H.x = (unsigned)h[0] | ((unsigned)h[1] << 16);
    H.y = (unsigned)h[2] | ((unsigned)h[3] << 16);
    H.z = (unsigned)h[4] | ((unsigned)h[5] << 16);
    H.w = (unsigned)h[6] | ((unsigned)h[7] << 16);
    L.x = (unsigned)l[0] | ((unsigned)l[1] << 16);
    L.y = (unsigned)l[2] | ((unsigned)l[3] << 16);
    L.z = (unsigned)l[4] | ((unsigned)l[5] << 16);
    L.w = (unsigned)l[6] | ((unsigned)l[7] << 16);
    int idx = (ks * 4 + jt) * 64 + lane;
    wfh[idx] = H; wfl[idx] = L;
  }
  if (tid < 64) {
    float t = 0.f;
    #pragma unroll
    for (int m = 0; m < 32; ++m) t = fmaf(b2[m], W3[m * 64 + tid], t);
    b2w3[tid] = t;
  }
}

// ---- histogram + dense conc extraction ----
__global__ void k_hist(const int* __restrict__ rxn_sub, const float* __restrict__ x,
                       int* __restrict__ counts, float* __restrict__ conc) {
  int t = blockIdx.x * blockDim.x + threadIdx.x;
  if (t < E_SUB / 4) {
    v4i r = __builtin_nontemporal_load((const v4i*)rxn_sub + t);
    atomicAdd(&counts[r.x], 1);
    atomicAdd(&counts[r.y], 1);
    atomicAdd(&counts[r.z], 1);
    atomicAdd(&counts[r.w], 1);
  }
  if (t < N_MET) conc[t] = __builtin_nontemporal_load(x + t * 8 + 3);
}

__global__ void k_scan1(const int* __restrict__ counts, int* __restrict__ bsums) {
  __shared__ int ss[SCAN_T];
  int b = blockIdx.x, t = threadIdx.x;
  int base = b * SCAN_CHUNK + t * SCAN_V;
  int s = 0;
  #pragma unroll
  for (int k = 0; k < SCAN_V; ++k) { int i = base + k; if (i < N_RXN) s += counts[i]; }
  ss[t] = s; __syncthreads();
  for (int d = SCAN_T / 2; d > 0; d >>= 1) {
    if (t < d) ss[t] += ss[t + d];
    __syncthreads();
  }
  if (t == 0) bsums[b] = ss[0];
}

__global__ void k_scan2(int* __restrict__ bsums) {
  __shared__ int ss[SCAN_T];
  int t = threadIdx.x;
  int v = (t < SCAN_NB) ? bsums[t] : 0;
  ss[t] = v; __syncthreads();
  for (int d = 1; d < SCAN_T; d <<= 1) {
    int a = (t >= d) ? ss[t - d] : 0;
    __syncthreads();
    ss[t] += a;
    __syncthreads();
  }
  if (t < SCAN_NB) bsums[t] = ss[t] - v;  // exclusive
}

__global__ void k_scan3(const int* __restrict__ counts, const int* __restrict__ bsums,
                        int* __restrict__ off, int* __restrict__ cursor) {
  __shared__ int ss[SCAN_T];
  int b = blockIdx.x, t = threadIdx.x;
  int base = b * SCAN_CHUNK + t * SCAN_V;
  int v[SCAN_V];
  int s = 0;
  #pragma unroll
  for (int k = 0; k < SCAN_V; ++k) { int i = base + k; v[k] = (i < N_RXN) ? counts[i] : 0; s += v[k]; }
  ss[t] = s; __syncthreads();
  for (int d = 1; d < SCAN_T; d <<= 1) {
    int a = (t >= d) ? ss[t - d] : 0;
    __syncthreads();
    ss[t] += a;
    __syncthreads();
  }
  int run = bsums[b] + ss[t] - s;
  #pragma unroll
  for (int k = 0; k < SCAN_V; ++k) {
    int i = base + k;
    if (i < N_RXN) { off[i] = run; cursor[i] = run; }
    run += v[k];
  }
  if (b == 0 && t == 0) off[N_RXN] = E_SUB;
}

// ---- scatter into CSR order: 8B record per edge {m, bitcast(sto)} ----
__global__ void k_scatter(const int* __restrict__ rxn_sub, const int* __restrict__ met_sub,
                          const float* __restrict__ sto_sub,
                          int* __restrict__ cursor, int2* __restrict__ edges8) {
  int e = blockIdx.x * blockDim.x + threadIdx.x;
  if (e < E_SUB) {
    int r = __builtin_nontemporal_load(rxn_sub + e);
    int m = __builtin_nontemporal_load(met_sub + e);
    float st = __builtin_nontemporal_load(sto_sub + e);
    int pos = atomicAdd(&cursor[r], 1);
    int2 rec; rec.x = m; rec.y = __float_as_int(st);
    edges8[pos] = rec;
  }
}

// ---- k_edge: wave-per-reaction edge tanh-sum; T -> bf16 hi/lo, row-major [r][64] ----
static __device__ __forceinline__ float edge_sum_lds(int o0, int o1, int estart,
                                                     const float2* ep,
                                                     float w1x, float w1y, float b1j) {
  float T0 = 0.f, T1 = 0.f;
  int c = o0;
  for (; c + 1 < o1; c += 2) {
    float2 e0 = ep[c - estart];
    float2 e1 = ep[c + 1 - estart];
    T0 += fast_tanh(fmaf(e0.x, w1x, fmaf(e0.y, w1y, b1j)));
    T1 += fast_tanh(fmaf(e1.x, w1x, fmaf(e1.y, w1y, b1j)));
  }
  if (c < o1) {
    float2 e0 = ep[c - estart];
    T0 += fast_tanh(fmaf(e0.x, w1x, fmaf(e0.y, w1y, b1j)));
  }
  return T0 + T1;
}

static __device__ __forceinline__ float edge_sum_glob(int o0, int o1,
                                                      const int2* edges8,
                                                      const float* conc,
                                                      float w1x, float w1y, float b1j) {
  float T = 0.f;
  for (int c = o0; c < o1; ++c) {
    int2 rec = edges8[c];
    float cc = conc[rec.x];
    T += fast_tanh(fmaf(cc, w1x, fmaf(__int_as_float(rec.y), w1y, b1j)));
  }
  return T;
}

__global__ __launch_bounds__(THREADS) void k_edge(
    const int* __restrict__ off, const int2* __restrict__ edges8,
    const float* __restrict__ conc,
    const float* __restrict__ W1, const float* __restrict__ b1,
    unsigned short* __restrict__ Thi, unsigned short* __restrict__ Tlo, int use_lo) {
  __shared__ int off_s[RXN_PER_BLK + 1];
  __shared__ float2 se[EDGE_CAP];

  int tid = threadIdx.x;
  int lane = tid & 63;
  int wv = tid >> 6;
  int R0 = blockIdx.x * RXN_PER_BLK;

  for (int i = tid; i <= RXN_PER_BLK; i += THREADS) {
    int r = R0 + i;
    off_s[i] = off[r > N_RXN ? N_RXN : r];
  }
  __syncthreads();
  int estart = off_s[0];
  int nE = off_s[RXN_PER_BLK] - estart;
  bool fits = (nE <= EDGE_CAP);
  if (fits) {
    // stage: coalesced 8B read + parallel conc gather (latency-hidden across 256 threads)
    for (int i = tid; i < nE; i += THREADS) {
      int2 rec = edges8[estart + i];
      se[i] = make_float2(conc[rec.x], __int_as_float(rec.y));
    }
  }

  float w1x = W1[lane], w1y = W1[64 + lane], b1j = b1[lane];

  int rbase = R0 + wv * 64;
  int o0l = off_s[wv * 64 + lane];
  int o1l = off_s[wv * 64 + lane + 1];

  __syncthreads();

  #pragma clang loop unroll(disable)
  for (int i = 0; i < 64; ++i) {
    int r = rbase + i;
    if (r >= N_RXN) break;  // uniform
    int o0 = bcast_i(o0l, i), o1 = bcast_i(o1l, i);
    float T = fits ? edge_sum_lds(o0, o1, estart, se, w1x, w1y, b1j)
                   : edge_sum_glob(o0, o1, edges8, conc, w1x, w1y, b1j);
    unsigned short hi = bf16_rn(T);
    Thi[r * 64 + lane] = hi;
    if (use_lo) {
      float hf = __uint_as_float(((unsigned)hi) << 16);
      Tlo[r * 64 + lane] = bf16_rn(T - hf);
    }
  }
}

// ---- k_mv: U = T @ W23 via MFMA (bf16 hi/lo), fused epilogue + consumption ----
__global__ __launch_bounds__(256) void k_mv(
    const int* __restrict__ off, const int2* __restrict__ edges8,
    const unsigned short* __restrict__ Thi, const unsigned short* __restrict__ Tlo,
    const uint4* __restrict__ wfh, const uint4* __restrict__ wfl,
    const float* __restrict__ b2w3, const float* __restrict__ b3,
    const float* __restrict__ W4, const float* __restrict__ b4,
    const float* __restrict__ log_k, int use_lo,
    float* __restrict__ v_pre, float* __restrict__ total) {
  __shared__ int soff[MV_RPB + 1];
  int tid = threadIdx.x, lane = tid & 63, w = tid >> 6;
  int B0 = blockIdx.x * MV_RPB;
  for (int i = tid; i <= MV_RPB; i += 256) {
    int r = B0 + i;
    soff[i] = off[r > N_RXN ? N_RXN : r];
  }
  __syncthreads();

  int R0 = B0 + w * 16;
  int col = lane & 15, rowg = lane >> 4;

  bf16x8 ah[2], al[2];
  {
    int rowelem = (R0 + col) * 64 + rowg * 8;
    const uint4* ph = (const uint4*)Thi;
    ah[0] = __builtin_bit_cast(bf16x8, ph[rowelem >> 3]);
    ah[1] = __builtin_bit_cast(bf16x8, ph[(rowelem + 32) >> 3]);
    if (use_lo) {
      const uint4* pl = (const uint4*)Tlo;
      al[0] = __builtin_bit_cast(bf16x8, pl[rowelem >> 3]);
      al[1] = __builtin_bit_cast(bf16x8, pl[(rowelem + 32) >> 3]);
    }
  }

  f32x4 acc[4];
  #pragma unroll
  for (int jt = 0; jt < 4; ++jt) acc[jt] = (f32x4){0.f, 0.f, 0.f, 0.f};

  #pragma unroll
  for (int jt = 0; jt < 4; ++jt) {
    #pragma unroll
    for (int ks = 0; ks < 2; ++ks) {
      int bidx = (ks * 4 + jt) * 64 + lane;
      bf16x8 bh = __builtin_bit_cast(bf16x8, wfh[bidx]);
      acc[jt] = __builtin_amdgcn_mfma_f32_16x16x32_bf16(ah[ks], bh, acc[jt], 0, 0, 0);
      if (use_lo) {
        bf16x8 bl = __builtin_bit_cast(bf16x8, wfl[bidx]);
        acc[jt] = __builtin_amdgcn_mfma_f32_16x16x32_bf16(ah[ks], bl, acc[jt], 0, 0, 0);
        acc[jt] = __builtin_amdgcn_mfma_f32_16x16x32_bf16(al[ks], bh, acc[jt], 0, 0, 0);
      }
    }
  }

  float w4c[4], bwc[4], b3c[4];
  #pragma unroll
  for (int jt = 0; jt < 4; ++jt) {
    int jj = jt * 16 + col;
    w4c[jt] = W4[jj]; bwc[jt] = b2w3[jj]; b3c[jt] = b3[jj];
  }
  float b40 = b4[0];

  float nq[4];
  #pragma unroll
  for (int q = 0; q < 4; ++q) {
    int idx = w * 16 + rowg * 4 + q;
    nq[q] = (float)(soff[idx + 1] - soff[idx]);
  }

  float vq[4];
  #pragma unroll
  for (int q = 0; q < 4; ++q) {
    float s = 0.f;
    #pragma unroll
    for (int jt = 0; jt < 4; ++jt) {
      float u = acc[jt][q] + nq[q] * bwc[jt] + b3c[jt];
      s += fast_tanh(u) * w4c[jt];
    }
    s += __shfl_xor(s, 1, 64);
    s += __shfl_xor(s, 2, 64);
    s += __shfl_xor(s, 4, 64);
    s += __shfl_xor(s, 8, 64);
    int r = R0 + rowg * 4 + q;
    float lk = (r < N_RXN) ? log_k[r] : 0.f;
    float racc = s + b40;
    float k10 = __expf(lk * 2.3025850929940457f);
    float sp = (racc > 15.f) ? racc : __logf(1.f + __expf(racc));
    vq[q] = k10 * sp;
  }

  if (col == 0) {
    #pragma unroll
    for (int q = 0; q < 4; ++q) {
      int r = R0 + rowg * 4 + q;
      if (r < N_RXN) v_pre[r] = vq[q];
    }
  }

  // consumption: 4 lanes per reaction walk its CSR slice
  int rloc = lane >> 2;
  float vdt = vq[(lane >> 2) & 3] * DT;
  int o0 = soff[w * 16 + rloc], o1 = soff[w * 16 + rloc + 1];
  for (int c = o0 + (lane & 3); c < o1; c += 4) {
    int2 e = edges8[c];
    atomic_add_f32(&total[e.x], __int_as_float(e.y) * vdt);
  }
}

__global__ void k_scale(const float* __restrict__ total, const float* __restrict__ conc,
                        float* __restrict__ met_scale) {
  int m = blockIdx.x * blockDim.x + threadIdx.x;
  if (m < N_MET) {
    float tot = total[m];
    float cc = conc[m];
    met_scale[m] = (tot > 1e-12f) ? fminf(cc / tot, 1.0f) : 1.0f;
  }
}

// ---- k_rscale: per-rxn min over CSR slice (4 lanes/rxn), fused vfin write. NO atomics ----
__global__ __launch_bounds__(256) void k_rscale(
    const int* __restrict__ off, const int2* __restrict__ edges8,
    const float* __restrict__ met_scale, const float* __restrict__ v_pre,
    float* __restrict__ vfin) {
  __shared__ int soff[MV_RPB + 1];
  int tid = threadIdx.x, lane = tid & 63, w = tid >> 6;
  int B0 = blockIdx.x * MV_RPB;
  for (int i = tid; i <= MV_RPB; i += 256) {
    int r = B0 + i;
    soff[i] = off[r > N_RXN ? N_RXN : r];
  }
  __syncthreads();

  int rloc = w * 16 + (lane >> 2);
  int o0 = soff[rloc], o1 = soff[rloc + 1];
  float sc = 1.0f;
  for (int c = o0 + (lane & 3); c < o1; c += 4) {
    sc = fminf(sc, met_scale[edges8[c].x]);
  }
  sc = fminf(sc, __shfl_xor(sc, 1, 64));
  sc = fminf(sc, __shfl_xor(sc, 2, 64));
  if ((lane & 3) == 0) {
    int r = B0 + rloc;
    if (r < N_RXN) vfin[r] = v_pre[r] * sc;
  }
}

__global__ void k_contrib(const int* __restrict__ met_all, const int* __restrict__ rxn_all,
                          const float* __restrict__ sto_all, const float* __restrict__ vfin,
                          float* __restrict__ dxdt) {
  int t = blockIdx.x * blockDim.x + threadIdx.x;
  if (t < E_ALL / 4) {
    v4i me = __builtin_nontemporal_load((const v4i*)met_all + t);
    v4i re = __builtin_nontemporal_load((const v4i*)rxn_all + t);
    v4f se = __builtin_nontemporal_load((const v4f*)sto_all + t);
    atomic_add_f32(&dxdt[me.x], se.x * vfin[re.x]);
    atomic_add_f32(&dxdt[me.y], se.y * vfin[re.y]);
    atomic_add_f32(&dxdt[me.z], se.z * vfin[re.z]);
    atomic_add_f32(&dxdt[me.w], se.w * vfin[re.w]);
  }
}

extern "C" void kernel_launch(void* const* d_in, const int* in_sizes, int n_in,
                              void* d_out, int out_size, void* d_ws, size_t ws_size,
                              hipStream_t stream) {
  const float* x       = (const float*)d_in[0];
  const int*   met_sub = (const int*)d_in[1];
  const int*   rxn_sub = (const int*)d_in[2];
  const float* sto_sub = (const float*)d_in[3];
  const int*   met_all = (const int*)d_in[4];
  const int*   rxn_all = (const int*)d_in[5];
  const float* sto_all = (const float*)d_in[6];
  const float* W1    = (const float*)d_in[7];
  const float* b1    = (const float*)d_in[8];
  const float* W2    = (const float*)d_in[9];
  const float* b2    = (const float*)d_in[10];
  const float* W3    = (const float*)d_in[11];
  const float* b3    = (const float*)d_in[12];
  const float* W4    = (const float*)d_in[13];
  const float* b4    = (const float*)d_in[14];
  const float* log_k = (const float*)d_in[15];
  float* dxdt = (float*)d_out;

  char* ws = (char*)d_ws;
  size_t p = 0;
  auto alloc = [&](size_t bytes) -> void* {
    void* r = (void*)(ws + p);
    p += (bytes + 255) & ~(size_t)255;
    return r;
  };
  int*    counts    = (int*)alloc(sizeof(int) * N_RXN);
  int*    off       = (int*)alloc(sizeof(int) * (N_RXN + 1));
  int*    cursor    = (int*)alloc(sizeof(int) * N_RXN);
  int*    bsums     = (int*)alloc(sizeof(int) * 1024);
  uint4*  wfh       = (uint4*)alloc(sizeof(uint4) * 512);
  uint4*  wfl      = (uint4*)alloc(sizeof(uint4) * 512);
  float*  b2w3      = (float*)alloc(sizeof(float) * 64);
  float*  v_pre     = (float*)alloc(sizeof(float) * N_RXN);
  float*  vfin      = (float*)alloc(sizeof(float) * N_RXN);
  float*  conc      = (float*)alloc(sizeof(float) * N_MET);
  float*  total     = (float*)alloc(sizeof(float) * N_MET);
  float*  met_scale = (float*)alloc(sizeof(float) * N_MET);
  int2*   edges8    = (int2*)alloc(sizeof(int2) * E_SUB);   // {m, sto} CSR-ordered
  unsigned short* Thi = (unsigned short*)alloc(sizeof(unsigned short) * (size_t)N_RXN_PAD * 64);
  size_t tlo_bytes = sizeof(unsigned short) * (size_t)N_RXN_PAD * 64;
  int use_lo = (p + tlo_bytes <= ws_size) ? 1 : 0;
  unsigned short* Tlo = use_lo ? (unsigned short*)alloc(tlo_bytes) : Thi;
  (void)in_sizes; (void)n_in; (void)out_size;

  hipMemsetAsync(counts, 0, sizeof(int) * N_RXN, stream);
  hipMemsetAsync(total, 0, sizeof(float) * N_MET, stream);
  hipMemsetAsync(dxdt, 0, sizeof(float) * N_MET, stream);

  k_pre<<<2, 256, 0, stream>>>(W2, W3, b2, wfh, wfl, b2w3);
  k_hist<<<(E_SUB / 4 + 255) / 256, 256, 0, stream>>>(rxn_sub, x, counts, conc);
  k_scan1<<<SCAN_NB, SCAN_T, 0, stream>>>(counts, bsums);
  k_scan2<<<1, SCAN_T, 0, stream>>>(bsums);
  k_scan3<<<SCAN_NB, SCAN_T, 0, stream>>>(counts, bsums, off, cursor);
  k_scatter<<<(E_SUB + 255) / 256, 256, 0, stream>>>(rxn_sub, met_sub, sto_sub,
                                                     cursor, edges8);
  k_edge<<<(N_RXN + RXN_PER_BLK - 1) / RXN_PER_BLK, THREADS, 0, stream>>>(
      off, edges8, conc, W1, b1, Thi, Tlo, use_lo);
  k_mv<<<(N_RXN + MV_RPB - 1) / MV_RPB, 256, 0, stream>>>(
      off, edges8, Thi, Tlo, wfh, wfl, b2w3, b3, W4, b4, log_k, use_lo, v_pre, total);
  k_scale<<<(N_MET + 255) / 256, 256, 0, stream>>>(total, conc, met_scale);
  k_rscale<<<(N_RXN + MV_RPB - 1) / MV_RPB, 256, 0, stream>>>(
      off, edges8, met_scale, v_pre, vfin);
  k_contrib<<<(E_ALL / 4 + 255) / 256, 256, 0, stream>>>(met_all, rxn_all, sto_all, vfin, dxdt);
}